// Round 5
// baseline (213.738 us; speedup 1.0000x reference)
//
#include <hip/hip_runtime.h>
#include <stdint.h>

typedef unsigned short u16;
typedef unsigned int   u32;

typedef float  f32x4  __attribute__((ext_vector_type(4)));
typedef __bf16 bf16x8 __attribute__((ext_vector_type(8)));

// ---------- helpers ----------
__device__ __forceinline__ u16 f2bf(float f) {
  union { float f; u32 u; } c; c.f = f;
  u32 u = c.u + 0x7fffu + ((c.u >> 16) & 1u);   // RNE; inputs finite
  return (u16)(u >> 16);
}
__device__ __forceinline__ float bf2f(u16 h) {
  union { u32 u; float f; } c; c.u = ((u32)h) << 16;
  return c.f;
}
__device__ __forceinline__ void gll16(const void* g, void* l) {
  __builtin_amdgcn_global_load_lds(
      (const __attribute__((address_space(1))) void*)g,
      (__attribute__((address_space(3))) void*)l, 16, 0, 0);
}

// ---------- fused fp32 -> bf16 convert: x, Wi, Wo in ONE dispatch ----------
__global__ __launch_bounds__(256)
void cvt_all(const float4* __restrict__ x,  uint2* __restrict__ xb,  int n4x,
             const float4* __restrict__ wi, uint2* __restrict__ wib,
             const float4* __restrict__ wo, uint2* __restrict__ wob, int n4w) {
  int i = blockIdx.x * 256 + threadIdx.x;
  const float4* s; uint2* d; int j;
  if (i < n4x)            { s = x;  d = xb;  j = i; }
  else if (i < n4x + n4w) { s = wi; d = wib; j = i - n4x; }
  else                    { s = wo; d = wob; j = i - n4x - n4w; }
  float4 v = s[j];
  uint2 o;
  o.x = (u32)f2bf(v.x) | ((u32)f2bf(v.y) << 16);
  o.y = (u32)f2bf(v.z) | ((u32)f2bf(v.w) << 16);
  d[j] = o;
}

// ---------- bf16 NT GEMM, 256x256 tile, m201-anatomy phase schedule ------
// C[M,N] = A[M,K] * B[N,K]^T. 512 thr = 8 waves (2M x 4N), per-wave 128x64.
// LDS 128 KiB = 2 buffers x [A-h0 | A-h1 | B-h0 | B-h1], [128 rows][64 k]
// bf16 each (16 KB linear blocks -> global_load_lds-compatible).
// Bank-conflict-free swizzle (verified r3: 3.1M -> 0): physical chunk
// p = (s*4+q) ^ (row&7), inverse pre-swizzle on the GLOBAL source.
// Phase anatomy (m201 template, the measured-3300cy/K-tile structure):
//   [ds_reads; (stage); s_barrier; lgkmcnt(0); setprio(1); 16 MFMA;
//    setprio(0); s_barrier]
// Reads and consuming MFMA in the SAME phase; per-wave lgkmcnt(0) after the
// barrier staggers waves into the MFMA cluster while the LDS pipe drains the
// batch -> LDS (~2300cy) and MFMA (~2500cy) overlap instead of serializing
// (rounds 1-4: 6200-7300cy/K-tile). No sched_barrier pinning (m141 lesson).
// K-tile = 4 Gray-quadrant phases (mh,nh): P1(0,0) reads A0+B0 (12),
// P2(0,1) reads B1 (4), P3(1,1) reads A1 (8), P4(1,0) reads none (both B
// halves stay register-resident; 24 reads/K-tile).
// Double-buffer: ALL 8 loads of tile t+1 issue in P1(t) -> buf^1 (region
// dead since bar2(P3,t-1)); certified by [vmcnt(0); s_barrier] at end of
// P4(t) -- per-wave drain + barrier = block-wide landing proof, ~2000cy of
// flight coverage so the drain is free (queue already empty).
template <bool OUT_BF16>
__global__ __launch_bounds__(512, 2)
void gemm_nt_256(const u16* __restrict__ A, const u16* __restrict__ B,
                 void* __restrict__ Cout, int M, int N, int K) {
  __shared__ u16 Ls[65536];                       // 128 KiB
  const int tid  = threadIdx.x;
  const int lane = tid & 63;
  const int wave = tid >> 6;                      // 0..7
  const int wm   = wave >> 2;                     // 0..1
  const int wn   = wave & 3;                      // 0..3
  const int ml   = lane & 15;
  const int q    = lane >> 4;                     // 0..3
  const int qx   = q ^ (ml & 3);                  // swizzled chunk bits [1:0]
  const int hx   = (ml >> 2) & 1;                 // XOR bit for chunk bit [2]

  // ---- XCD-locality swizzle (bijection; gridDim.x == 4, gridDim.y % 8 == 0)
  const int flat = blockIdx.y * 4 + blockIdx.x;
  const int xcd  = flat & 7;
  const int slot = flat >> 3;
  const int mt   = xcd * (gridDim.y >> 3) + (slot >> 2);
  const int nt   = slot & 3;
  const int m0   = mt * 256;
  const int n0   = nt * 256;

  // ---- staging: thread t lands at LDS (row tid>>3 (+64), chunk tid&7);
  // inverse 3-bit swizzle on the global chunk so reads recover logical k.
  const int srr = tid >> 3;                       // 0..63
  const int gc  = (tid & 7) ^ ((tid >> 3) & 7);
  const u16* Agb = A + (size_t)(m0 + srr) * K + gc * 8;
  const u16* Bgb = B + (size_t)(n0 + srr) * K + gc * 8;
  char* LsB = (char*)Ls;
  const int wlds = wave * 1024;

  auto stageAll = [&](int bufb, int k0) {         // 8 x gll16: tile -> bufb
#pragma unroll
    for (int h = 0; h < 2; ++h) {
      char* d = LsB + bufb + h * 16384 + wlds;
      gll16(Agb + (size_t)(h * 128) * K + k0, d);
      gll16(Agb + (size_t)(h * 128 + 64) * K + k0, d + 8192);
    }
#pragma unroll
    for (int h = 0; h < 2; ++h) {
      char* d = LsB + bufb + 32768 + h * 16384 + wlds;
      gll16(Bgb + (size_t)(h * 128) * K + k0, d);
      gll16(Bgb + (size_t)(h * 128 + 64) * K + k0, d + 8192);
    }
  };

  // ---- fragment read bases (u16 index within Ls) ----
  // physical chunk for k-substep s: p = ((s^hx)<<2) | qx.
  const int aB_ = wm * 8192 + ml * 64 + qx * 8;
  const int bB_ = 16384 + (wn >> 1) * 8192 + ((wn & 1) * 64 + ml) * 64 + qx * 8;

  f32x4  acc[8][4] = {};
  bf16x8 af[4][2];                                // A frags, current mh
  bf16x8 bq[2][2][2];                             // B frags [nh][j][s], both nh resident

  auto rdA = [&](int bw, int mh) {
#pragma unroll
    for (int i = 0; i < 4; ++i)
#pragma unroll
      for (int s = 0; s < 2; ++s)
        af[i][s] = *reinterpret_cast<const bf16x8*>(
            &Ls[bw + aB_ + mh * 4096 + i * 1024 + (s ^ hx) * 32]);
  };
  auto rdB = [&](int bw, int nh) {
#pragma unroll
    for (int j = 0; j < 2; ++j)
#pragma unroll
      for (int s = 0; s < 2; ++s)
        bq[nh][j][s] = *reinterpret_cast<const bf16x8*>(
            &Ls[bw + bB_ + nh * 2048 + j * 1024 + (s ^ hx) * 32]);
  };
  auto mfmaQ = [&](int mh, int nh) {              // one C-quadrant x K=64
    __builtin_amdgcn_s_setprio(1);
#pragma unroll
    for (int s = 0; s < 2; ++s)
#pragma unroll
      for (int i = 0; i < 4; ++i)
#pragma unroll
        for (int j = 0; j < 2; ++j)
          acc[mh * 4 + i][nh * 2 + j] = __builtin_amdgcn_mfma_f32_16x16x32_bf16(
              af[i][s], bq[nh][j][s], acc[mh * 4 + i][nh * 2 + j], 0, 0, 0);
    __builtin_amdgcn_s_setprio(0);
  };

  // ---- prologue: tile0 -> buf0; certify landing ----
  stageAll(0, 0);
  asm volatile("s_waitcnt vmcnt(0)" ::: "memory");
  __builtin_amdgcn_s_barrier();

  const int NT = K >> 6;                           // 16
  int bufb = 0;
  for (int t = 0; t < NT; ++t, bufb ^= 65536) {
    const int bw = bufb >> 1;                      // u16 base, current buffer
    // P1 (mh0,nh0): reads A0+B0; stage ALL of tile t+1 -> buf^1
    rdA(bw, 0); rdB(bw, 0);
    if (t + 1 < NT) stageAll(bufb ^ 65536, (t + 1) << 6);
    __builtin_amdgcn_s_barrier();
    asm volatile("s_waitcnt lgkmcnt(0)" ::: "memory");
    mfmaQ(0, 0);
    __builtin_amdgcn_s_barrier();
    // P2 (mh0,nh1): reads B1
    rdB(bw, 1);
    __builtin_amdgcn_s_barrier();
    asm volatile("s_waitcnt lgkmcnt(0)" ::: "memory");
    mfmaQ(0, 1);
    __builtin_amdgcn_s_barrier();
    // P3 (mh1,nh1): reads A1
    rdA(bw, 1);
    __builtin_amdgcn_s_barrier();
    asm volatile("s_waitcnt lgkmcnt(0)" ::: "memory");
    mfmaQ(1, 1);
    __builtin_amdgcn_s_barrier();
    // P4 (mh1,nh0): no reads; then certify tile t+1 landed for next iter
    mfmaQ(1, 0);
    asm volatile("s_waitcnt vmcnt(0)" ::: "memory");
    __builtin_amdgcn_s_barrier();
  }

  // ---- epilogue: C/D frag row = q*4 + reg, col = lane&15 (verified) ----
  const int rowb = m0 + wm * 128 + q * 4;
  const int colb = n0 + wn * 64 + ml;
#pragma unroll
  for (int mf = 0; mf < 8; ++mf)
#pragma unroll
    for (int nf = 0; nf < 4; ++nf)
#pragma unroll
      for (int r = 0; r < 4; ++r) {
        size_t idx = (size_t)(rowb + mf * 16 + r) * N + (colb + nf * 16);
        float val = acc[mf][nf][r];
        if (OUT_BF16) ((u16*)Cout)[idx] = f2bf(val);
        else          ((float*)Cout)[idx] = val;
      }
}

// ---------- analytic Gaussian attention: 13-tap conv along L ----------
__global__ __launch_bounds__(256)
void gauss_conv(const u16* __restrict__ v, u16* __restrict__ att, int L) {
  constexpr float wt[13] = {
    1.5229979744712628e-08f, 3.7266531720786709e-06f, 3.3546262790251185e-04f,
    1.1108996538242306e-02f, 1.3533528323661270e-01f, 6.0653065971263342e-01f,
    1.0f,
    6.0653065971263342e-01f, 1.3533528323661270e-01f, 1.1108996538242306e-02f,
    3.3546262790251185e-04f, 3.7266531720786709e-06f, 1.5229979744712628e-08f
  };
  const int t  = threadIdx.x;
  const int fg = t & 15;
  const int li = t >> 4;
  const int l  = blockIdx.x * 16 + li;
  const int h  = blockIdx.y;             // head: block-uniform
  const int b  = blockIdx.z;
  int c;
  switch (h) {
    case 0: case 5: c = l;     break;
    case 1: case 6: c = l - 1; break;
    case 2: case 7: c = l + 1; break;
    case 3:         c = 0;     break;
    default:        c = L - 1; break;
  }
  const int fbase = h * 128 + fg * 8;
  const u16* vb = v + (size_t)b * L * 1024 + fbase;

  float a[8] = {};
  float Z = 0.f;
#pragma unroll
  for (int d = -6; d <= 6; ++d) {
    int idx = c + d;
    bool ok = (idx >= 0) && (idx < L);
    int ic_ = idx < 0 ? 0 : (idx >= L ? L - 1 : idx);
    float w = ok ? wt[d + 6] : 0.f;
    Z += w;
    uint4 p = *reinterpret_cast<const uint4*>(vb + (size_t)ic_ * 1024);
    a[0] = fmaf(w, bf2f((u16)(p.x & 0xffffu)), a[0]);
    a[1] = fmaf(w, bf2f((u16)(p.x >> 16)),     a[1]);
    a[2] = fmaf(w, bf2f((u16)(p.y & 0xffffu)), a[2]);
    a[3] = fmaf(w, bf2f((u16)(p.y >> 16)),     a[3]);
    a[4] = fmaf(w, bf2f((u16)(p.z & 0xffffu)), a[4]);
    a[5] = fmaf(w, bf2f((u16)(p.z >> 16)),     a[5]);
    a[6] = fmaf(w, bf2f((u16)(p.w & 0xffffu)), a[6]);
    a[7] = fmaf(w, bf2f((u16)(p.w >> 16)),     a[7]);
  }
  float inv = 1.0f / Z;
  uint4 o;
  o.x = (u32)f2bf(a[0] * inv) | ((u32)f2bf(a[1] * inv) << 16);
  o.y = (u32)f2bf(a[2] * inv) | ((u32)f2bf(a[3] * inv) << 16);
  o.z = (u32)f2bf(a[4] * inv) | ((u32)f2bf(a[5] * inv) << 16);
  o.w = (u32)f2bf(a[6] * inv) | ((u32)f2bf(a[7] * inv) << 16);
  *reinterpret_cast<uint4*>(att + (size_t)(b * L + l) * 1024 + fbase) = o;
}

// ---------- launch ----------
extern "C" void kernel_launch(void* const* d_in, const int* in_sizes, int n_in,
                              void* d_out, int out_size, void* d_ws, size_t ws_size,
                              hipStream_t stream) {
  const int Bb = 8, L = 2048, E = 1024;
  const int M = Bb * L, N = E, K = E;

  const float* x  = (const float*)d_in[0];
  const float* Wi = (const float*)d_in[1];
  const float* Wo = (const float*)d_in[2];
  float* out = (float*)d_out;

  // ws layout (bf16): [xb 32Mi | v 32Mi | wib 2Mi | wob 2Mi]; att reuses xb
  size_t offV  = (size_t)M * E * 2;
  size_t offWi = offV + (size_t)M * E * 2;
  size_t offWo = offWi + (size_t)E * E * 2;
  size_t need  = offWo + (size_t)E * E * 2;
  if (ws_size < need) return;

  u16* xb  = (u16*)d_ws;
  u16* v   = (u16*)((char*)d_ws + offV);
  u16* wib = (u16*)((char*)d_ws + offWi);
  u16* wob = (u16*)((char*)d_ws + offWo);
  u16* att = xb;  // reuse: conv runs after GEMM1 completes

  int n4x = M * E / 4, n4w = E * E / 4;
  int nblk = (n4x + 2 * n4w) / 256;
  cvt_all<<<nblk, 256, 0, stream>>>((const float4*)x, (uint2*)xb, n4x,
                                    (const float4*)Wi, (uint2*)wib,
                                    (const float4*)Wo, (uint2*)wob, n4w);

  dim3 gg(N / 256, M / 256);   // (4, 64) -> 256 blocks, 1 per CU
  gemm_nt_256<true ><<<gg, 512, 0, stream>>>(xb,  wib, v,   M, N, K);
  gauss_conv<<<dim3(L / 16, 8, Bb), 256, 0, stream>>>(v, att, L);
  gemm_nt_256<false><<<gg, 512, 0, stream>>>(att, wob, out, M, N, K);
}

// Round 6
// 208.175 us; speedup vs baseline: 1.0267x; 1.0267x over previous
//
#include <hip/hip_runtime.h>
#include <stdint.h>

typedef unsigned short u16;
typedef unsigned int   u32;

typedef float  f32x4  __attribute__((ext_vector_type(4)));
typedef __bf16 bf16x8 __attribute__((ext_vector_type(8)));

// ---------- helpers ----------
__device__ __forceinline__ u16 f2bf(float f) {
  union { float f; u32 u; } c; c.f = f;
  u32 u = c.u + 0x7fffu + ((c.u >> 16) & 1u);   // RNE; inputs finite
  return (u16)(u >> 16);
}
__device__ __forceinline__ float bf2f(u16 h) {
  union { u32 u; float f; } c; c.u = ((u32)h) << 16;
  return c.f;
}
__device__ __forceinline__ void gll16(const void* g, void* l) {
  __builtin_amdgcn_global_load_lds(
      (const __attribute__((address_space(1))) void*)g,
      (__attribute__((address_space(3))) void*)l, 16, 0, 0);
}

// ---------- fused fp32 -> bf16 convert: x, Wi, Wo in ONE dispatch ----------
__global__ __launch_bounds__(256)
void cvt_all(const float4* __restrict__ x,  uint2* __restrict__ xb,  int n4x,
             const float4* __restrict__ wi, uint2* __restrict__ wib,
             const float4* __restrict__ wo, uint2* __restrict__ wob, int n4w) {
  int i = blockIdx.x * 256 + threadIdx.x;
  const float4* s; uint2* d; int j;
  if (i < n4x)            { s = x;  d = xb;  j = i; }
  else if (i < n4x + n4w) { s = wi; d = wib; j = i - n4x; }
  else                    { s = wo; d = wob; j = i - n4x - n4w; }
  float4 v = s[j];
  uint2 o;
  o.x = (u32)f2bf(v.x) | ((u32)f2bf(v.y) << 16);
  o.y = (u32)f2bf(v.z) | ((u32)f2bf(v.w) << 16);
  d[j] = o;
}

// ---------- bf16 NT GEMM, 256x256 tile, single-buffer region rotation ----
// C[M,N] = A[M,K] * B[N,K]^T. 512 thr = 8 waves (2M x 4N), per-wave 128x64.
// LDS 64 KiB, 4 regions of 8192 u16: Au0 | Au1 | Bv0 | Bv1.
//   A-unit u  = tile rows {u*64..u*64+63} U {128+u*64..128+u*64+63}
//               (the rows quadrant (mh=u) reads, across both wm halves)
//   B-unit v  = cols {wn*64+v*32 .. +32} for all wn (nh=v slices)
// Gray-quadrant phases per K-tile: P1(0,0) reads Au0+Bv0 (12 b128);
// P2(0,1) reads Bv1 (4); P3(1,1) reads Au1 (8); P4(1,0) regs-only.
// Each region's ONLY LDS read is in one phase -> dead at that phase's
// closing barrier -> tile t+1 stages into it next phase (region rotation,
// no double buffer): P2: stage Au0+Bv0(t+1); P3: Bv1(t+1); P4: Au1(t+1).
// Counted vmcnt ONLY (the m218 T4 lever; r5's vmcnt(0)-per-tile drain cost
// exactly ~900cy x 16 tiles): per-wave FIFO [Au0,Bv0 @P2 | Bv1 @P3 | Au1 @P4]
//   P1-end vmcnt(2)  -> certifies Bv1(t)   (staged P3(t-1))
//   P2-end vmcnt(4)  -> certifies Au1(t)   (staged P4(t-1))
//   P4     vmcnt(4)  -> certifies Au0,Bv0(t+1) for P1(t+1)
// Steady-state in-flight 2..8, never 0; ~2 phases (~1600cy) flight/half-tile.
// Phase anatomy (m201): [ds_reads; stage; s_barrier; lgkmcnt(0); setprio(1);
// 16 MFMA; setprio(0); vmcnt(N); s_barrier].
// Bank-conflict-free swizzle (verified r3: 3.1M -> 0): phys chunk
// p = (s*4+q) ^ (row&7); inverse pre-swizzle on the GLOBAL source; row&7 ==
// ml&7 for every read row and == rl&7 for every staged row (unchanged).
template <bool OUT_BF16>
__global__ __launch_bounds__(512, 2)
void gemm_nt_256(const u16* __restrict__ A, const u16* __restrict__ B,
                 void* __restrict__ Cout, int M, int N, int K) {
  __shared__ u16 Ls[32768];                       // 64 KiB
  const int tid  = threadIdx.x;
  const int lane = tid & 63;
  const int wave = tid >> 6;                      // 0..7
  const int wm   = wave >> 2;                     // 0..1
  const int wn   = wave & 3;                      // 0..3
  const int ml   = lane & 15;
  const int q    = lane >> 4;                     // 0..3
  const int qx   = q ^ (ml & 3);                  // swizzled chunk bits [1:0]
  const int hx   = (ml >> 2) & 1;                 // XOR bit for chunk bit [2]

  // ---- XCD-locality swizzle (bijection; gridDim.x == 4, gridDim.y % 8 == 0)
  const int flat = blockIdx.y * 4 + blockIdx.x;
  const int xcd  = flat & 7;
  const int slot = flat >> 3;
  const int mt   = xcd * (gridDim.y >> 3) + (slot >> 2);
  const int nt   = slot & 3;
  const int m0   = mt * 256;
  const int n0   = nt * 256;

  // ---- staging: thread t -> region-local row rl = t>>3 (+64 for 2nd gll),
  // phys chunk t&7, global logical chunk gc = (t&7)^(rl&7) (inverse swizzle).
  const int rl = tid >> 3;                        // 0..63
  const int gc = (tid & 7) ^ (rl & 7);
  const u16* Abase = A + (size_t)m0 * K + gc * 8;
  const u16* Bbase = B + (size_t)n0 * K + gc * 8;
  char* LsB = (char*)Ls;
  const int wlds = wave * 1024;

  auto stageA = [&](int u, int k0) {              // region Au<u>, 2 x gll16
    char* d = LsB + u * 16384 + wlds;
    gll16(Abase + (size_t)(u * 64 + rl) * K + k0, d);
    gll16(Abase + (size_t)(u * 64 + rl + 128) * K + k0, d + 8192);
  };
  auto stageB = [&](int v, int k0) {              // region Bv<v>, 2 x gll16
    char* d = LsB + 32768 + v * 16384 + wlds;
    const int g1 = (rl >> 5) * 64 + v * 32 + (rl & 31);
    gll16(Bbase + (size_t)g1 * K + k0, d);
    gll16(Bbase + (size_t)(g1 + 128) * K + k0, d + 8192);
  };

  // ---- fragment read bases (u16 index within Ls) ----
  // A region mh: [wm sub 64 rows][row i*16+ml][chunk]; B region nh:
  // [wn sub 32 rows][row j*16+ml][chunk]. phys chunk off = ((s^hx)*4|qx)*8.
  const int aB_ = wm * 4096 + ml * 64 + qx * 8;
  const int bB_ = 16384 + wn * 2048 + ml * 64 + qx * 8;

  f32x4  acc[8][4] = {};
  bf16x8 af[4][2];                                // A frags, current mh
  bf16x8 bq[2][2][2];                             // B frags [nh][j][s], both resident

  auto rdA = [&](int mh) {
#pragma unroll
    for (int i = 0; i < 4; ++i)
#pragma unroll
      for (int s = 0; s < 2; ++s)
        af[i][s] = *reinterpret_cast<const bf16x8*>(
            &Ls[mh * 8192 + aB_ + i * 1024 + (s ^ hx) * 32]);
  };
  auto rdB = [&](int nh) {
#pragma unroll
    for (int j = 0; j < 2; ++j)
#pragma unroll
      for (int s = 0; s < 2; ++s)
        bq[nh][j][s] = *reinterpret_cast<const bf16x8*>(
            &Ls[bB_ + nh * 8192 + j * 1024 + (s ^ hx) * 32]);
  };
  auto mfmaQ = [&](int mh, int nh) {              // one C-quadrant x K=64
    __builtin_amdgcn_s_setprio(1);
#pragma unroll
    for (int s = 0; s < 2; ++s)
#pragma unroll
      for (int i = 0; i < 4; ++i)
#pragma unroll
        for (int j = 0; j < 2; ++j)
          acc[mh * 4 + i][nh * 2 + j] = __builtin_amdgcn_mfma_f32_16x16x32_bf16(
              af[i][s], bq[nh][j][s], acc[mh * 4 + i][nh * 2 + j], 0, 0, 0);
    __builtin_amdgcn_s_setprio(0);
  };

  // ---- prologue: tile0 -> all 4 regions; certify; enter steady state ----
  stageA(0, 0); stageB(0, 0); stageB(1, 0); stageA(1, 0);
  asm volatile("s_waitcnt vmcnt(0)" ::: "memory");
  __builtin_amdgcn_s_barrier();

  const int NT = K >> 6;                           // 16
  for (int t = 0; t < NT; ++t) {
    const int  kn  = (t + 1) << 6;
    const bool stg = (t + 1 < NT);
    // P1 (0,0): read Au0+Bv0
    rdA(0); rdB(0);
    __builtin_amdgcn_s_barrier();
    asm volatile("s_waitcnt lgkmcnt(0)" ::: "memory");
    mfmaQ(0, 0);
    asm volatile("s_waitcnt vmcnt(2)" ::: "memory");   // Bv1(t) landed
    __builtin_amdgcn_s_barrier();
    // P2 (0,1): read Bv1; stage Au0+Bv0(t+1) into dead regions
    rdB(1);
    if (stg) { stageA(0, kn); stageB(0, kn); }
    __builtin_amdgcn_s_barrier();
    asm volatile("s_waitcnt lgkmcnt(0)" ::: "memory");
    mfmaQ(0, 1);
    if (stg) { asm volatile("s_waitcnt vmcnt(4)" ::: "memory"); }  // Au1(t)
    else     { asm volatile("s_waitcnt vmcnt(0)" ::: "memory"); }
    __builtin_amdgcn_s_barrier();
    // P3 (1,1): read Au1; stage Bv1(t+1)
    rdA(1);
    if (stg) stageB(1, kn);
    __builtin_amdgcn_s_barrier();
    asm volatile("s_waitcnt lgkmcnt(0)" ::: "memory");
    mfmaQ(1, 1);
    __builtin_amdgcn_s_barrier();
    // P4 (1,0): regs only; stage Au1(t+1); certify Au0+Bv0(t+1)
    if (stg) stageA(1, kn);
    mfmaQ(1, 0);
    asm volatile("s_waitcnt vmcnt(4)" ::: "memory");
    __builtin_amdgcn_s_barrier();
  }

  // ---- epilogue: C/D frag row = q*4 + reg, col = lane&15 (verified) ----
  const int rowb = m0 + wm * 128 + q * 4;
  const int colb = n0 + wn * 64 + ml;
#pragma unroll
  for (int mf = 0; mf < 8; ++mf)
#pragma unroll
    for (int nf = 0; nf < 4; ++nf)
#pragma unroll
      for (int r = 0; r < 4; ++r) {
        size_t idx = (size_t)(rowb + mf * 16 + r) * N + (colb + nf * 16);
        float val = acc[mf][nf][r];
        if (OUT_BF16) ((u16*)Cout)[idx] = f2bf(val);
        else          ((float*)Cout)[idx] = val;
      }
}

// ---------- analytic Gaussian attention: 13-tap conv along L ----------
__global__ __launch_bounds__(256)
void gauss_conv(const u16* __restrict__ v, u16* __restrict__ att, int L) {
  constexpr float wt[13] = {
    1.5229979744712628e-08f, 3.7266531720786709e-06f, 3.3546262790251185e-04f,
    1.1108996538242306e-02f, 1.3533528323661270e-01f, 6.0653065971263342e-01f,
    1.0f,
    6.0653065971263342e-01f, 1.3533528323661270e-01f, 1.1108996538242306e-02f,
    3.3546262790251185e-04f, 3.7266531720786709e-06f, 1.5229979744712628e-08f
  };
  const int t  = threadIdx.x;
  const int fg = t & 15;
  const int li = t >> 4;
  const int l  = blockIdx.x * 16 + li;
  const int h  = blockIdx.y;             // head: block-uniform
  const int b  = blockIdx.z;
  int c;
  switch (h) {
    case 0: case 5: c = l;     break;
    case 1: case 6: c = l - 1; break;
    case 2: case 7: c = l + 1; break;
    case 3:         c = 0;     break;
    default:        c = L - 1; break;
  }
  const int fbase = h * 128 + fg * 8;
  const u16* vb = v + (size_t)b * L * 1024 + fbase;

  float a[8] = {};
  float Z = 0.f;
#pragma unroll
  for (int d = -6; d <= 6; ++d) {
    int idx = c + d;
    bool ok = (idx >= 0) && (idx < L);
    int ic_ = idx < 0 ? 0 : (idx >= L ? L - 1 : idx);
    float w = ok ? wt[d + 6] : 0.f;
    Z += w;
    uint4 p = *reinterpret_cast<const uint4*>(vb + (size_t)ic_ * 1024);
    a[0] = fmaf(w, bf2f((u16)(p.x & 0xffffu)), a[0]);
    a[1] = fmaf(w, bf2f((u16)(p.x >> 16)),     a[1]);
    a[2] = fmaf(w, bf2f((u16)(p.y & 0xffffu)), a[2]);
    a[3] = fmaf(w, bf2f((u16)(p.y >> 16)),     a[3]);
    a[4] = fmaf(w, bf2f((u16)(p.z & 0xffffu)), a[4]);
    a[5] = fmaf(w, bf2f((u16)(p.z >> 16)),     a[5]);
    a[6] = fmaf(w, bf2f((u16)(p.w & 0xffffu)), a[6]);
    a[7] = fmaf(w, bf2f((u16)(p.w >> 16)),     a[7]);
  }
  float inv = 1.0f / Z;
  uint4 o;
  o.x = (u32)f2bf(a[0] * inv) | ((u32)f2bf(a[1] * inv) << 16);
  o.y = (u32)f2bf(a[2] * inv) | ((u32)f2bf(a[3] * inv) << 16);
  o.z = (u32)f2bf(a[4] * inv) | ((u32)f2bf(a[5] * inv) << 16);
  o.w = (u32)f2bf(a[6] * inv) | ((u32)f2bf(a[7] * inv) << 16);
  *reinterpret_cast<uint4*>(att + (size_t)(b * L + l) * 1024 + fbase) = o;
}

// ---------- launch ----------
extern "C" void kernel_launch(void* const* d_in, const int* in_sizes, int n_in,
                              void* d_out, int out_size, void* d_ws, size_t ws_size,
                              hipStream_t stream) {
  const int Bb = 8, L = 2048, E = 1024;
  const int M = Bb * L, N = E, K = E;

  const float* x  = (const float*)d_in[0];
  const float* Wi = (const float*)d_in[1];
  const float* Wo = (const float*)d_in[2];
  float* out = (float*)d_out;

  // ws layout (bf16): [xb 32Mi | v 32Mi | wib 2Mi | wob 2Mi]; att reuses xb
  size_t offV  = (size_t)M * E * 2;
  size_t offWi = offV + (size_t)M * E * 2;
  size_t offWo = offWi + (size_t)E * E * 2;
  size_t need  = offWo + (size_t)E * E * 2;
  if (ws_size < need) return;

  u16* xb  = (u16*)d_ws;
  u16* v   = (u16*)((char*)d_ws + offV);
  u16* wib = (u16*)((char*)d_ws + offWi);
  u16* wob = (u16*)((char*)d_ws + offWo);
  u16* att = xb;  // reuse: conv runs after GEMM1 completes

  int n4x = M * E / 4, n4w = E * E / 4;
  int nblk = (n4x + 2 * n4w) / 256;
  cvt_all<<<nblk, 256, 0, stream>>>((const float4*)x, (uint2*)xb, n4x,
                                    (const float4*)Wi, (uint2*)wib,
                                    (const float4*)Wo, (uint2*)wob, n4w);

  dim3 gg(N / 256, M / 256);   // (4, 64) -> 256 blocks, 1 per CU
  gemm_nt_256<true ><<<gg, 512, 0, stream>>>(xb,  wib, v,   M, N, K);
  gauss_conv<<<dim3(L / 16, 8, Bb), 256, 0, stream>>>(v, att, L);
  gemm_nt_256<false><<<gg, 512, 0, stream>>>(att, wob, out, M, N, K);
}